// Round 6
// baseline (29.880 us; speedup 1.0000x reference)
//
#include <hip/hip_runtime.h>
#include <math.h>

#define EPS_REG 1e-6f
#define MIN_EIG_F 1e-4f
#define RB 8        // rows per block in fused beta pass
// NOTE: sized for N=2048 (harness shape). LDS planes + reduction buffer
// alias the same 48 KB region.

// ---------- 3x3 helpers ----------

__device__ __forceinline__ void sym_inv3(const float m[3][3], float o[3][3]) {
    float c00 = m[1][1]*m[2][2] - m[1][2]*m[2][1];
    float c01 = m[1][2]*m[2][0] - m[1][0]*m[2][2];
    float c02 = m[1][0]*m[2][1] - m[1][1]*m[2][0];
    float det = m[0][0]*c00 + m[0][1]*c01 + m[0][2]*c02;
    float inv = 1.0f / det;
    o[0][0] = c00*inv;
    o[1][0] = c01*inv;
    o[2][0] = c02*inv;
    o[0][1] = (m[0][2]*m[2][1]-m[0][1]*m[2][2])*inv;
    o[1][1] = (m[0][0]*m[2][2]-m[0][2]*m[2][0])*inv;
    o[2][1] = (m[0][1]*m[2][0]-m[0][0]*m[2][1])*inv;
    o[0][2] = (m[0][1]*m[1][2]-m[0][2]*m[1][1])*inv;
    o[1][2] = (m[0][2]*m[1][0]-m[0][0]*m[1][2])*inv;
    o[2][2] = (m[0][0]*m[1][1]-m[0][1]*m[1][0])*inv;
}

__device__ __forceinline__ void rodrigues(float w0, float w1, float w2, float R[3][3]) {
    float th2 = w0*w0 + w1*w1 + w2*w2;
    float th = sqrtf(th2);
    float a, b;
    if (th < 1e-4f) { a = 1.0f - th2*(1.0f/6.0f); b = 0.5f - th2*(1.0f/24.0f); }
    else            { a = sinf(th)/th;            b = (1.0f - cosf(th))/th2; }
    R[0][0] = 1.0f + b*(w0*w0 - th2); R[0][1] = -a*w2 + b*w0*w1;        R[0][2] =  a*w1 + b*w0*w2;
    R[1][0] =  a*w2 + b*w0*w1;        R[1][1] = 1.0f + b*(w1*w1 - th2); R[1][2] = -a*w0 + b*w1*w2;
    R[2][0] = -a*w1 + b*w0*w2;        R[2][1] =  a*w0 + b*w1*w2;        R[2][2] = 1.0f + b*(w2*w2 - th2);
}

__device__ __forceinline__ void jrot(float A[3][3], float V[3][3], int p, int q) {
    float apq = A[p][q];
    if (fabsf(apq) < 1e-20f) return;
    float theta = (A[q][q] - A[p][p]) / (2.0f * apq);
    float t = 1.0f / (fabsf(theta) + sqrtf(1.0f + theta*theta));
    if (theta < 0.0f) t = -t;
    float c = 1.0f / sqrtf(1.0f + t*t);
    float s = t * c;
    int r = 3 - p - q;
    float apq_t = t*apq;
    A[p][p] -= apq_t;
    A[q][q] += apq_t;
    A[p][q] = 0.0f; A[q][p] = 0.0f;
    float arp = A[r][p], arq = A[r][q];
    A[r][p] = c*arp - s*arq; A[p][r] = A[r][p];
    A[r][q] = s*arp + c*arq; A[q][r] = A[r][q];
    #pragma unroll
    for (int k = 0; k < 3; k++) {
        float vkp = V[k][p], vkq = V[k][q];
        V[k][p] = c*vkp - s*vkq;
        V[k][q] = s*vkp + c*vkq;
    }
}

__device__ __forceinline__ void compute_S_point(const float* __restrict__ sq9,
                                                const float* __restrict__ ph3,
                                                float sv[6]) {
    float m[3][3], lq[3][3];
    #pragma unroll
    for (int i = 0; i < 3; i++)
        #pragma unroll
        for (int j = 0; j < 3; j++) m[i][j] = sq9[i*3 + j];
    m[0][0] += EPS_REG; m[1][1] += EPS_REG; m[2][2] += EPS_REG;
    sym_inv3(m, lq);
    float R[3][3];
    rodrigues(ph3[0], ph3[1], ph3[2], R);
    float U[3][3];
    #pragma unroll
    for (int i = 0; i < 3; i++)
        #pragma unroll
        for (int j = 0; j < 3; j++)
            U[i][j] = lq[i][0]*R[0][j] + lq[i][1]*R[1][j] + lq[i][2]*R[2][j];
    sv[0] = R[0][0]*U[0][0] + R[1][0]*U[1][0] + R[2][0]*U[2][0];
    sv[1] = R[0][0]*U[0][1] + R[1][0]*U[1][1] + R[2][0]*U[2][1];
    sv[2] = R[0][0]*U[0][2] + R[1][0]*U[1][2] + R[2][0]*U[2][2];
    sv[3] = R[0][1]*U[0][1] + R[1][1]*U[1][1] + R[2][1]*U[2][1];
    sv[4] = R[0][1]*U[0][2] + R[1][1]*U[1][2] + R[2][1]*U[2][2];
    sv[5] = R[0][2]*U[0][2] + R[1][2]*U[1][2] + R[2][2]*U[2][2];
}

// ---------- kernel 1: S-in-LDS + one pass over beta ----------
// Block: 256 threads, RB=8 rows. Phase 0: compute S for the ENTIRE batch
// into LDS planes splane[c][N] (redundant per block; inputs are L2-resident).
// Phase 1: stream beta once; T row-sums (reg-tiled) + column partials.
// Phase 2: LDS transpose reduction (aliases the S planes) -> T.
__global__ __launch_bounds__(256) void mega_beta_kernel(
        const float* __restrict__ Sq,
        const float* __restrict__ phi,
        const float* __restrict__ beta,
        float* __restrict__ T,
        float* __restrict__ partial,  // B * (N/RB) * N
        int B, int N) {
    __shared__ float smem[12288];     // 48 KB: splane[6][2048]  |  red[256][48]
    __shared__ float red2[4][48];

    int tid = threadIdx.x;
    int grow0 = blockIdx.x * RB;          // global row start (B*N space)
    int b = grow0 / N;
    int chunksPerB = N / RB;
    int chunk = (grow0 - b * N) / RB;

    // ---- prefetch first beta j-tile (hides HBM latency under phase 0) ----
    float4 pre[RB];
    {
        int c0 = 4 * tid;
        #pragma unroll
        for (int r = 0; r < RB; r++)
            pre[r] = *(const float4*)(beta + (size_t)(grow0 + r) * N + c0);
    }

    // ---- phase 0: S for entire batch into LDS planes ----
    {
        const float* sqb = Sq  + (size_t)b * N * 9;
        const float* phb = phi + (size_t)b * N * 3;
        int npts = N / 256;               // 8 points per thread
        for (int ph = 0; ph < npts; ph++) {
            int p = ph * 256 + tid;
            float sv[6];
            compute_S_point(sqb + (size_t)p * 9, phb + (size_t)p * 3, sv);
            #pragma unroll
            for (int c = 0; c < 6; c++) smem[c * 2048 + p] = sv[c];
        }
    }
    __syncthreads();

    // ---- phase 1: stream beta ----
    float acc[RB][6];
    #pragma unroll
    for (int r = 0; r < RB; r++)
        #pragma unroll
        for (int c = 0; c < 6; c++) acc[r][c] = 0.0f;

    int jtiles = N / 1024;                // 4 cols/thread * 256 threads
    for (int jt = 0; jt < jtiles; jt++) {
        int c0 = jt * 1024 + 4 * tid;
        float4 s0 = *(const float4*)&smem[0*2048 + c0];
        float4 s1 = *(const float4*)&smem[1*2048 + c0];
        float4 s2 = *(const float4*)&smem[2*2048 + c0];
        float4 s3 = *(const float4*)&smem[3*2048 + c0];
        float4 s4v = *(const float4*)&smem[4*2048 + c0];
        float4 s5 = *(const float4*)&smem[5*2048 + c0];

        float csum0 = 0.f, csum1 = 0.f, csum2 = 0.f, csum3 = 0.f;
        #pragma unroll
        for (int r = 0; r < RB; r++) {
            float4 w4 = (jt == 0) ? pre[r]
                      : *(const float4*)(beta + (size_t)(grow0 + r) * N + c0);
            csum0 += w4.x; csum1 += w4.y; csum2 += w4.z; csum3 += w4.w;
            acc[r][0] += w4.x*s0.x + w4.y*s0.y + w4.z*s0.z + w4.w*s0.w;
            acc[r][1] += w4.x*s1.x + w4.y*s1.y + w4.z*s1.z + w4.w*s1.w;
            acc[r][2] += w4.x*s2.x + w4.y*s2.y + w4.z*s2.z + w4.w*s2.w;
            acc[r][3] += w4.x*s3.x + w4.y*s3.y + w4.z*s3.z + w4.w*s3.w;
            acc[r][4] += w4.x*s4v.x + w4.y*s4v.y + w4.z*s4v.z + w4.w*s4v.w;
            acc[r][5] += w4.x*s5.x + w4.y*s5.y + w4.z*s5.z + w4.w*s5.w;
        }
        *(float4*)(partial + ((size_t)b * chunksPerB + chunk) * N + c0) =
            make_float4(csum0, csum1, csum2, csum3);
    }
    __syncthreads();   // all S reads done; smem can be reused

    // ---- phase 2: LDS transpose reduction (red[256][48] aliases smem) ----
    #pragma unroll
    for (int r = 0; r < RB; r++)
        #pragma unroll
        for (int c = 0; c < 6; c++)
            smem[tid * 48 + r * 6 + c] = acc[r][c];
    __syncthreads();
    if (tid < 192) {
        int v = tid % 48, grp = tid / 48;   // 4 groups of 64 threads' rows
        float s = 0.0f;
        #pragma unroll 8
        for (int r = 0; r < 64; r++) s += smem[(grp * 64 + r) * 48 + v];
        red2[grp][v] = s;
    }
    __syncthreads();
    if (tid < 48) {
        float v = red2[0][tid] + red2[1][tid] + red2[2][tid] + red2[3][tid];
        T[(size_t)grow0 * 6 + tid] = v;     // 48 contiguous floats
    }
}

// ---------- kernel 2: finalize (merged chunk-reduce; 256 thr / 64 pts) ----------
__global__ __launch_bounds__(256) void finalize_kernel(
        const float* __restrict__ Sp,
        const float* __restrict__ Sq,
        const float* __restrict__ phi,
        const float* __restrict__ T,
        const float* __restrict__ partial, // B*(N/RB)*N
        float* __restrict__ out,
        int B, int N) {
    int tid  = threadIdx.x;
    int lane = tid & 63;
    int sub  = tid >> 6;            // 0..3
    int p0   = blockIdx.x * 64;     // 64 points per block
    int BN   = B * N;
    int b    = p0 / N;
    int i0   = p0 - b * N;
    int chunks = N / RB;

    __shared__ float redc[4][64];
    __shared__ float sp_s[576], sq_s[576], ph_s[192], t_s[384];
    __shared__ float o1_s[576], o2_s[576];

    // --- parallel column-sum: each sub-wave handles chunks/4 chunks ---
    int cpg = chunks / 4;
    float csp = 0.0f;
    const float* pp = partial + ((size_t)b * chunks + sub * cpg) * N + (i0 + lane);
    #pragma unroll 8
    for (int c = 0; c < cpg; c++) { csp += *pp; pp += (size_t)N; }
    redc[sub][lane] = csp;

    // --- stage per-point inputs (coalesced float4) ---
    {
        const float4* s1 = (const float4*)(Sp + (size_t)p0 * 9);
        const float4* s2 = (const float4*)(Sq + (size_t)p0 * 9);
        if (tid < 144) { ((float4*)sp_s)[tid] = s1[tid]; ((float4*)sq_s)[tid] = s2[tid]; }
        const float4* s3 = (const float4*)(phi + (size_t)p0 * 3);
        if (tid < 48) ((float4*)ph_s)[tid] = s3[tid];
        const float4* s4 = (const float4*)(T + (size_t)p0 * 6);
        if (tid < 96) ((float4*)t_s)[tid] = s4[tid];
    }
    __syncthreads();

    if (tid < 64) {
        float cs = redc[0][lane] + redc[1][lane] + redc[2][lane] + redc[3][lane];

        float m[3][3], lp[3][3], lq[3][3];
        #pragma unroll
        for (int i = 0; i < 3; i++)
            #pragma unroll
            for (int j = 0; j < 3; j++) m[i][j] = sq_s[lane*9 + i*3 + j];
        m[0][0] += EPS_REG; m[1][1] += EPS_REG; m[2][2] += EPS_REG;
        sym_inv3(m, lq);
        #pragma unroll
        for (int i = 0; i < 3; i++)
            #pragma unroll
            for (int j = 0; j < 3; j++) m[i][j] = sp_s[lane*9 + i*3 + j];
        m[0][0] += EPS_REG; m[1][1] += EPS_REG; m[2][2] += EPS_REG;
        sym_inv3(m, lp);

        float R[3][3];
        rodrigues(ph_s[lane*3], ph_s[lane*3+1], ph_s[lane*3+2], R);

        const float* tp = t_s + lane * 6;
        float Tm[3][3] = {{tp[0],tp[1],tp[2]},{tp[1],tp[3],tp[4]},{tp[2],tp[4],tp[5]}};

        // M = lp + R*Tm*R^T + cs*lq
        float U[3][3], M[3][3];
        #pragma unroll
        for (int ii = 0; ii < 3; ii++)
            #pragma unroll
            for (int jj = 0; jj < 3; jj++)
                U[ii][jj] = R[ii][0]*Tm[0][jj] + R[ii][1]*Tm[1][jj] + R[ii][2]*Tm[2][jj];
        #pragma unroll
        for (int ii = 0; ii < 3; ii++)
            #pragma unroll
            for (int jj = 0; jj < 3; jj++) {
                float min_ij = U[ii][0]*R[jj][0] + U[ii][1]*R[jj][1] + U[ii][2]*R[jj][2];
                M[ii][jj] = lp[ii][jj] + min_ij + cs * lq[ii][jj];
            }
        float A[3][3];
        #pragma unroll
        for (int ii = 0; ii < 3; ii++)
            #pragma unroll
            for (int jj = 0; jj < 3; jj++) A[ii][jj] = 0.5f * (M[ii][jj] + M[jj][ii]);

        float V[3][3] = {{1,0,0},{0,1,0},{0,0,1}};
        #pragma unroll
        for (int sweep = 0; sweep < 6; sweep++) {
            jrot(A, V, 0, 1);
            jrot(A, V, 0, 2);
            jrot(A, V, 1, 2);
        }
        float w0 = fmaxf(A[0][0], MIN_EIG_F);
        float w1 = fmaxf(A[1][1], MIN_EIG_F);
        float w2 = fmaxf(A[2][2], MIN_EIG_F);
        float iw0 = 1.0f/w0, iw1 = 1.0f/w1, iw2 = 1.0f/w2;

        #pragma unroll
        for (int ii = 0; ii < 3; ii++)
            #pragma unroll
            for (int jj = 0; jj < 3; jj++) {
                o1_s[lane*9 + ii*3 + jj] = V[ii][0]*w0*V[jj][0] + V[ii][1]*w1*V[jj][1] + V[ii][2]*w2*V[jj][2];
                o2_s[lane*9 + ii*3 + jj] = V[ii][0]*iw0*V[jj][0] + V[ii][1]*iw1*V[jj][1] + V[ii][2]*iw2*V[jj][2];
            }
    }
    __syncthreads();

    // --- coalesced float4 stores of both outputs ---
    float4* d1 = (float4*)(out + (size_t)p0 * 9);
    float4* d2 = (float4*)(out + (size_t)BN * 9 + (size_t)p0 * 9);
    if (tid < 144) { d1[tid] = ((float4*)o1_s)[tid]; d2[tid] = ((float4*)o2_s)[tid]; }
}

extern "C" void kernel_launch(void* const* d_in, const int* in_sizes, int n_in,
                              void* d_out, int out_size, void* d_ws, size_t ws_size,
                              hipStream_t stream) {
    const float* Sp   = (const float*)d_in[0];
    const float* Sq   = (const float*)d_in[1];
    const float* phi  = (const float*)d_in[2];
    const float* beta = (const float*)d_in[3];

    int BN = in_sizes[2] / 3;                 // B*N
    int N  = (int)((long long)in_sizes[3] / BN);
    int B  = BN / N;

    float* ws = (float*)d_ws;
    float* T  = ws;                        // BN*6
    float* partial = T + (size_t)BN * 6;   // B*(N/RB)*N

    float* outf = (float*)d_out;

    mega_beta_kernel<<<BN / RB, 256, 0, stream>>>(Sq, phi, beta, T, partial, B, N);

    finalize_kernel<<<BN / 64, 256, 0, stream>>>(Sp, Sq, phi, T, partial, outf, B, N);
}

// Round 7
// 27.312 us; speedup vs baseline: 1.0940x; 1.0940x over previous
//
#include <hip/hip_runtime.h>
#include <math.h>

#define EPS_REG 1e-6f
#define MIN_EIG_F 1e-4f
#define RB 8        // rows per block in fused beta pass

// ---------- 3x3 helpers ----------

__device__ __forceinline__ void sym_inv3(const float m[3][3], float o[3][3]) {
    float c00 = m[1][1]*m[2][2] - m[1][2]*m[2][1];
    float c01 = m[1][2]*m[2][0] - m[1][0]*m[2][2];
    float c02 = m[1][0]*m[2][1] - m[1][1]*m[2][0];
    float det = m[0][0]*c00 + m[0][1]*c01 + m[0][2]*c02;
    float inv = 1.0f / det;
    o[0][0] = c00*inv;
    o[1][0] = c01*inv;
    o[2][0] = c02*inv;
    o[0][1] = (m[0][2]*m[2][1]-m[0][1]*m[2][2])*inv;
    o[1][1] = (m[0][0]*m[2][2]-m[0][2]*m[2][0])*inv;
    o[2][1] = (m[0][1]*m[2][0]-m[0][0]*m[2][1])*inv;
    o[0][2] = (m[0][1]*m[1][2]-m[0][2]*m[1][1])*inv;
    o[1][2] = (m[0][2]*m[1][0]-m[0][0]*m[1][2])*inv;
    o[2][2] = (m[0][0]*m[1][1]-m[0][1]*m[1][0])*inv;
}

__device__ __forceinline__ void rodrigues(float w0, float w1, float w2, float R[3][3]) {
    float th2 = w0*w0 + w1*w1 + w2*w2;
    float th = sqrtf(th2);
    float a, b;
    if (th < 1e-4f) { a = 1.0f - th2*(1.0f/6.0f); b = 0.5f - th2*(1.0f/24.0f); }
    else            { a = sinf(th)/th;            b = (1.0f - cosf(th))/th2; }
    R[0][0] = 1.0f + b*(w0*w0 - th2); R[0][1] = -a*w2 + b*w0*w1;        R[0][2] =  a*w1 + b*w0*w2;
    R[1][0] =  a*w2 + b*w0*w1;        R[1][1] = 1.0f + b*(w1*w1 - th2); R[1][2] = -a*w0 + b*w1*w2;
    R[2][0] = -a*w1 + b*w0*w2;        R[2][1] =  a*w0 + b*w1*w2;        R[2][2] = 1.0f + b*(w2*w2 - th2);
}

__device__ __forceinline__ void jrot(float A[3][3], float V[3][3], int p, int q) {
    float apq = A[p][q];
    if (fabsf(apq) < 1e-20f) return;
    float theta = (A[q][q] - A[p][p]) / (2.0f * apq);
    float t = 1.0f / (fabsf(theta) + sqrtf(1.0f + theta*theta));
    if (theta < 0.0f) t = -t;
    float c = 1.0f / sqrtf(1.0f + t*t);
    float s = t * c;
    int r = 3 - p - q;
    float apq_t = t*apq;
    A[p][p] -= apq_t;
    A[q][q] += apq_t;
    A[p][q] = 0.0f; A[q][p] = 0.0f;
    float arp = A[r][p], arq = A[r][q];
    A[r][p] = c*arp - s*arq; A[p][r] = A[r][p];
    A[r][q] = s*arp + c*arq; A[q][r] = A[r][q];
    #pragma unroll
    for (int k = 0; k < 3; k++) {
        float vkp = V[k][p], vkq = V[k][q];
        V[k][p] = c*vkp - s*vkq;
        V[k][q] = s*vkp + c*vkq;
    }
}

// ---------- kernel 1: per-point S = R^T Lq R -> SoA planes ----------
// Splanes layout: [6][BN]; write per plane is lane-consecutive (coalesced).
__global__ __launch_bounds__(64) void precompute_S_kernel(
        const float* __restrict__ Sq,
        const float* __restrict__ phi,
        float* __restrict__ Splanes,
        int BN) {
    __shared__ float sq_s[576];   // 64 pts * 9
    __shared__ float ph_s[192];   // 64 pts * 3
    int tid = threadIdx.x;
    int p0 = blockIdx.x * 64;

    const float4* src = (const float4*)(Sq + (size_t)p0 * 9);
    #pragma unroll
    for (int i = tid; i < 144; i += 64) ((float4*)sq_s)[i] = src[i];
    const float4* psrc = (const float4*)(phi + (size_t)p0 * 3);
    if (tid < 48) ((float4*)ph_s)[tid] = psrc[tid];
    __syncthreads();

    float m[3][3], lq[3][3];
    #pragma unroll
    for (int i = 0; i < 3; i++)
        #pragma unroll
        for (int j = 0; j < 3; j++) m[i][j] = sq_s[tid*9 + i*3 + j];
    m[0][0] += EPS_REG; m[1][1] += EPS_REG; m[2][2] += EPS_REG;
    sym_inv3(m, lq);

    float R[3][3];
    rodrigues(ph_s[tid*3], ph_s[tid*3+1], ph_s[tid*3+2], R);

    float U[3][3];
    #pragma unroll
    for (int i = 0; i < 3; i++)
        #pragma unroll
        for (int j = 0; j < 3; j++)
            U[i][j] = lq[i][0]*R[0][j] + lq[i][1]*R[1][j] + lq[i][2]*R[2][j];
    float sv[6];
    sv[0] = R[0][0]*U[0][0] + R[1][0]*U[1][0] + R[2][0]*U[2][0];
    sv[1] = R[0][0]*U[0][1] + R[1][0]*U[1][1] + R[2][0]*U[2][1];
    sv[2] = R[0][0]*U[0][2] + R[1][0]*U[1][2] + R[2][0]*U[2][2];
    sv[3] = R[0][1]*U[0][1] + R[1][1]*U[1][1] + R[2][1]*U[2][1];
    sv[4] = R[0][1]*U[0][2] + R[1][1]*U[1][2] + R[2][1]*U[2][2];
    sv[5] = R[0][2]*U[0][2] + R[1][2]*U[1][2] + R[2][2]*U[2][2];
    #pragma unroll
    for (int c = 0; c < 6; c++)
        Splanes[(size_t)c * BN + p0 + tid] = sv[c];   // coalesced per plane
}

// ---------- kernel 2 (fused): one pass over beta ----------
// Block: 256 threads, RB=8 rows. Thread owns 4 consecutive cols per j-tile.
// S read from SoA planes -> every load lane-consecutive float4 (coalesced).
//   T[row] = sum_j beta[row][j] * S[j]   (LDS transpose reduction)
//   partial[b][chunk][col] = sum_{r in block} beta[r][col]
__global__ __launch_bounds__(256) void fused_beta_kernel(
        const float* __restrict__ beta,
        const float* __restrict__ Splanes,
        float* __restrict__ T,
        float* __restrict__ partial,  // B * (N/RB) * N
        int B, int N, int BN) {
    int tid = threadIdx.x;
    int grow0 = blockIdx.x * RB;         // global row start (B*N space)
    int b = grow0 / N;
    int chunksPerB = N / RB;
    int chunk = (grow0 - b * N) / RB;

    float acc[RB][6];
    #pragma unroll
    for (int r = 0; r < RB; r++)
        #pragma unroll
        for (int c = 0; c < 6; c++) acc[r][c] = 0.0f;

    int jtiles = N / 1024;               // 4 cols/thread * 256 threads
    for (int jt = 0; jt < jtiles; jt++) {
        int c0 = jt * 1024 + 4 * tid;
        float4 s[6];
        #pragma unroll
        for (int c = 0; c < 6; c++)
            s[c] = *(const float4*)(Splanes + (size_t)c * BN + (size_t)b * N + c0);

        float csum0 = 0.f, csum1 = 0.f, csum2 = 0.f, csum3 = 0.f;
        #pragma unroll
        for (int r = 0; r < RB; r++) {
            float4 w4 = *(const float4*)(beta + (size_t)(grow0 + r) * N + c0);
            csum0 += w4.x; csum1 += w4.y; csum2 += w4.z; csum3 += w4.w;
            #pragma unroll
            for (int c = 0; c < 6; c++)
                acc[r][c] += w4.x*s[c].x + w4.y*s[c].y + w4.z*s[c].z + w4.w*s[c].w;
        }
        *(float4*)(partial + ((size_t)b * chunksPerB + chunk) * N + c0) =
            make_float4(csum0, csum1, csum2, csum3);
    }

    // ---- LDS transpose reduction: 256 threads x 48 values -> 48 sums ----
    __shared__ float red[256][48];   // stride 48: 2-way bank alias (free)
    __shared__ float red2[4][48];
    #pragma unroll
    for (int r = 0; r < RB; r++)
        #pragma unroll
        for (int c = 0; c < 6; c++)
            red[tid][r * 6 + c] = acc[r][c];
    __syncthreads();
    if (tid < 192) {
        int v = tid % 48, grp = tid / 48;   // 4 groups of 64 rows
        float s = 0.0f;
        #pragma unroll 8
        for (int r = 0; r < 64; r++) s += red[grp * 64 + r][v];
        red2[grp][v] = s;
    }
    __syncthreads();
    if (tid < 48) {
        float v = red2[0][tid] + red2[1][tid] + red2[2][tid] + red2[3][tid];
        T[(size_t)grow0 * 6 + tid] = v;     // 48 contiguous floats
    }
}

// ---------- kernel 3: finalize (128 blocks, 32 pts/block, 256 thr) ----------
__global__ __launch_bounds__(256) void finalize_kernel(
        const float* __restrict__ Sp,
        const float* __restrict__ Sq,
        const float* __restrict__ phi,
        const float* __restrict__ T,
        const float* __restrict__ partial, // B*(N/RB)*N
        float* __restrict__ out,
        int B, int N) {
    int tid   = threadIdx.x;
    int lane32 = tid & 31;
    int grp    = tid >> 5;          // 0..7
    int p0   = blockIdx.x * 32;     // 32 points per block
    int BN   = B * N;
    int b    = p0 / N;
    int i0   = p0 - b * N;
    int chunks = N / RB;            // 256

    __shared__ float redc[8][32];
    __shared__ float sp_s[288], sq_s[288], ph_s[96], t_s[192];
    __shared__ float o1_s[288], o2_s[288];

    // --- parallel column-sum: 8 groups x 32 chunks each ---
    int cpg = chunks / 8;           // 32
    float csp = 0.0f;
    const float* pp = partial + ((size_t)b * chunks + grp * cpg) * N + (i0 + lane32);
    #pragma unroll 8
    for (int c = 0; c < cpg; c++) { csp += *pp; pp += (size_t)N; }
    redc[grp][lane32] = csp;

    // --- stage per-point inputs (coalesced float4) ---
    {
        const float4* s1 = (const float4*)(Sp + (size_t)p0 * 9);
        const float4* s2 = (const float4*)(Sq + (size_t)p0 * 9);
        if (tid < 72) { ((float4*)sp_s)[tid] = s1[tid]; ((float4*)sq_s)[tid] = s2[tid]; }
        const float4* s3 = (const float4*)(phi + (size_t)p0 * 3);
        if (tid < 24) ((float4*)ph_s)[tid] = s3[tid];
        const float4* s4 = (const float4*)(T + (size_t)p0 * 6);
        if (tid < 48) ((float4*)t_s)[tid] = s4[tid];
    }
    __syncthreads();

    if (tid < 32) {
        float cs = 0.0f;
        #pragma unroll
        for (int g = 0; g < 8; g++) cs += redc[g][tid];

        float m[3][3], lp[3][3], lq[3][3];
        #pragma unroll
        for (int i = 0; i < 3; i++)
            #pragma unroll
            for (int j = 0; j < 3; j++) m[i][j] = sq_s[tid*9 + i*3 + j];
        m[0][0] += EPS_REG; m[1][1] += EPS_REG; m[2][2] += EPS_REG;
        sym_inv3(m, lq);
        #pragma unroll
        for (int i = 0; i < 3; i++)
            #pragma unroll
            for (int j = 0; j < 3; j++) m[i][j] = sp_s[tid*9 + i*3 + j];
        m[0][0] += EPS_REG; m[1][1] += EPS_REG; m[2][2] += EPS_REG;
        sym_inv3(m, lp);

        float R[3][3];
        rodrigues(ph_s[tid*3], ph_s[tid*3+1], ph_s[tid*3+2], R);

        const float* tp = t_s + tid * 6;
        float Tm[3][3] = {{tp[0],tp[1],tp[2]},{tp[1],tp[3],tp[4]},{tp[2],tp[4],tp[5]}};

        // M = lp + R*Tm*R^T + cs*lq
        float U[3][3], M[3][3];
        #pragma unroll
        for (int ii = 0; ii < 3; ii++)
            #pragma unroll
            for (int jj = 0; jj < 3; jj++)
                U[ii][jj] = R[ii][0]*Tm[0][jj] + R[ii][1]*Tm[1][jj] + R[ii][2]*Tm[2][jj];
        #pragma unroll
        for (int ii = 0; ii < 3; ii++)
            #pragma unroll
            for (int jj = 0; jj < 3; jj++) {
                float min_ij = U[ii][0]*R[jj][0] + U[ii][1]*R[jj][1] + U[ii][2]*R[jj][2];
                M[ii][jj] = lp[ii][jj] + min_ij + cs * lq[ii][jj];
            }
        float A[3][3];
        #pragma unroll
        for (int ii = 0; ii < 3; ii++)
            #pragma unroll
            for (int jj = 0; jj < 3; jj++) A[ii][jj] = 0.5f * (M[ii][jj] + M[jj][ii]);

        float V[3][3] = {{1,0,0},{0,1,0},{0,0,1}};
        #pragma unroll
        for (int sweep = 0; sweep < 6; sweep++) {
            jrot(A, V, 0, 1);
            jrot(A, V, 0, 2);
            jrot(A, V, 1, 2);
        }
        float w0 = fmaxf(A[0][0], MIN_EIG_F);
        float w1 = fmaxf(A[1][1], MIN_EIG_F);
        float w2 = fmaxf(A[2][2], MIN_EIG_F);
        float iw0 = 1.0f/w0, iw1 = 1.0f/w1, iw2 = 1.0f/w2;

        #pragma unroll
        for (int ii = 0; ii < 3; ii++)
            #pragma unroll
            for (int jj = 0; jj < 3; jj++) {
                o1_s[tid*9 + ii*3 + jj] = V[ii][0]*w0*V[jj][0] + V[ii][1]*w1*V[jj][1] + V[ii][2]*w2*V[jj][2];
                o2_s[tid*9 + ii*3 + jj] = V[ii][0]*iw0*V[jj][0] + V[ii][1]*iw1*V[jj][1] + V[ii][2]*iw2*V[jj][2];
            }
    }
    __syncthreads();

    // --- coalesced float4 stores of both outputs ---
    float4* d1 = (float4*)(out + (size_t)p0 * 9);
    float4* d2 = (float4*)(out + (size_t)BN * 9 + (size_t)p0 * 9);
    if (tid < 72) { d1[tid] = ((float4*)o1_s)[tid]; d2[tid] = ((float4*)o2_s)[tid]; }
}

extern "C" void kernel_launch(void* const* d_in, const int* in_sizes, int n_in,
                              void* d_out, int out_size, void* d_ws, size_t ws_size,
                              hipStream_t stream) {
    const float* Sp   = (const float*)d_in[0];
    const float* Sq   = (const float*)d_in[1];
    const float* phi  = (const float*)d_in[2];
    const float* beta = (const float*)d_in[3];

    int BN = in_sizes[2] / 3;                 // B*N
    int N  = (int)((long long)in_sizes[3] / BN);
    int B  = BN / N;

    float* ws = (float*)d_ws;
    float* Splanes = ws;                        // 6*BN
    float* T       = Splanes + (size_t)BN * 6;  // BN*6
    float* partial = T + (size_t)BN * 6;        // B*(N/RB)*N

    float* outf = (float*)d_out;

    precompute_S_kernel<<<BN / 64, 64, 0, stream>>>(Sq, phi, Splanes, BN);

    fused_beta_kernel<<<BN / RB, 256, 0, stream>>>(beta, Splanes, T, partial, B, N, BN);

    finalize_kernel<<<BN / 32, 256, 0, stream>>>(Sp, Sq, phi, T, partial, outf, B, N);
}

// Round 8
// 26.305 us; speedup vs baseline: 1.1359x; 1.0383x over previous
//
#include <hip/hip_runtime.h>
#include <math.h>

#define EPS_REG 1e-6f
#define MIN_EIG_F 1e-4f
#define RB 8        // rows per block in fused beta pass

// ---------- 3x3 helpers ----------

__device__ __forceinline__ void sym_inv3(const float m[3][3], float o[3][3]) {
    float c00 = m[1][1]*m[2][2] - m[1][2]*m[2][1];
    float c01 = m[1][2]*m[2][0] - m[1][0]*m[2][2];
    float c02 = m[1][0]*m[2][1] - m[1][1]*m[2][0];
    float det = m[0][0]*c00 + m[0][1]*c01 + m[0][2]*c02;
    float inv = 1.0f / det;
    o[0][0] = c00*inv;
    o[1][0] = c01*inv;
    o[2][0] = c02*inv;
    o[0][1] = (m[0][2]*m[2][1]-m[0][1]*m[2][2])*inv;
    o[1][1] = (m[0][0]*m[2][2]-m[0][2]*m[2][0])*inv;
    o[2][1] = (m[0][1]*m[2][0]-m[0][0]*m[2][1])*inv;
    o[0][2] = (m[0][1]*m[1][2]-m[0][2]*m[1][1])*inv;
    o[1][2] = (m[0][2]*m[1][0]-m[0][0]*m[1][2])*inv;
    o[2][2] = (m[0][0]*m[1][1]-m[0][1]*m[1][0])*inv;
}

__device__ __forceinline__ void rodrigues(float w0, float w1, float w2, float R[3][3]) {
    float th2 = w0*w0 + w1*w1 + w2*w2;
    float th = sqrtf(th2);
    float a, b;
    if (th < 1e-4f) { a = 1.0f - th2*(1.0f/6.0f); b = 0.5f - th2*(1.0f/24.0f); }
    else            { a = sinf(th)/th;            b = (1.0f - cosf(th))/th2; }
    R[0][0] = 1.0f + b*(w0*w0 - th2); R[0][1] = -a*w2 + b*w0*w1;        R[0][2] =  a*w1 + b*w0*w2;
    R[1][0] =  a*w2 + b*w0*w1;        R[1][1] = 1.0f + b*(w1*w1 - th2); R[1][2] = -a*w0 + b*w1*w2;
    R[2][0] = -a*w1 + b*w0*w2;        R[2][1] =  a*w0 + b*w1*w2;        R[2][2] = 1.0f + b*(w2*w2 - th2);
}

__device__ __forceinline__ void jrot(float A[3][3], float V[3][3], int p, int q) {
    float apq = A[p][q];
    if (fabsf(apq) < 1e-20f) return;
    float theta = (A[q][q] - A[p][p]) / (2.0f * apq);
    float t = 1.0f / (fabsf(theta) + sqrtf(1.0f + theta*theta));
    if (theta < 0.0f) t = -t;
    float c = 1.0f / sqrtf(1.0f + t*t);
    float s = t * c;
    int r = 3 - p - q;
    float apq_t = t*apq;
    A[p][p] -= apq_t;
    A[q][q] += apq_t;
    A[p][q] = 0.0f; A[q][p] = 0.0f;
    float arp = A[r][p], arq = A[r][q];
    A[r][p] = c*arp - s*arq; A[p][r] = A[r][p];
    A[r][q] = s*arp + c*arq; A[q][r] = A[r][q];
    #pragma unroll
    for (int k = 0; k < 3; k++) {
        float vkp = V[k][p], vkq = V[k][q];
        V[k][p] = c*vkp - s*vkq;
        V[k][q] = s*vkp + c*vkq;
    }
}

// ---------- kernel 1: per-point S = R^T Lq R -> SoA planes ----------
__global__ __launch_bounds__(64) void precompute_S_kernel(
        const float* __restrict__ Sq,
        const float* __restrict__ phi,
        float* __restrict__ Splanes,
        int BN) {
    __shared__ float sq_s[576];
    __shared__ float ph_s[192];
    int tid = threadIdx.x;
    int p0 = blockIdx.x * 64;

    const float4* src = (const float4*)(Sq + (size_t)p0 * 9);
    #pragma unroll
    for (int i = tid; i < 144; i += 64) ((float4*)sq_s)[i] = src[i];
    const float4* psrc = (const float4*)(phi + (size_t)p0 * 3);
    if (tid < 48) ((float4*)ph_s)[tid] = psrc[tid];
    __syncthreads();

    float m[3][3], lq[3][3];
    #pragma unroll
    for (int i = 0; i < 3; i++)
        #pragma unroll
        for (int j = 0; j < 3; j++) m[i][j] = sq_s[tid*9 + i*3 + j];
    m[0][0] += EPS_REG; m[1][1] += EPS_REG; m[2][2] += EPS_REG;
    sym_inv3(m, lq);

    float R[3][3];
    rodrigues(ph_s[tid*3], ph_s[tid*3+1], ph_s[tid*3+2], R);

    float U[3][3];
    #pragma unroll
    for (int i = 0; i < 3; i++)
        #pragma unroll
        for (int j = 0; j < 3; j++)
            U[i][j] = lq[i][0]*R[0][j] + lq[i][1]*R[1][j] + lq[i][2]*R[2][j];
    float sv[6];
    sv[0] = R[0][0]*U[0][0] + R[1][0]*U[1][0] + R[2][0]*U[2][0];
    sv[1] = R[0][0]*U[0][1] + R[1][0]*U[1][1] + R[2][0]*U[2][1];
    sv[2] = R[0][0]*U[0][2] + R[1][0]*U[1][2] + R[2][0]*U[2][2];
    sv[3] = R[0][1]*U[0][1] + R[1][1]*U[1][1] + R[2][1]*U[2][1];
    sv[4] = R[0][1]*U[0][2] + R[1][1]*U[1][2] + R[2][1]*U[2][2];
    sv[5] = R[0][2]*U[0][2] + R[1][2]*U[1][2] + R[2][2]*U[2][2];
    #pragma unroll
    for (int c = 0; c < 6; c++)
        Splanes[(size_t)c * BN + p0 + tid] = sv[c];
}

// ---------- kernel 2 (fused): one pass over beta, 2-tile straight-line ----------
__device__ __forceinline__ void beta_tile(
        const float* __restrict__ beta,
        const float* __restrict__ Splanes,
        float* __restrict__ partial,
        int grow0, int b, int N, int BN,
        int chunksPerB, int chunk, int c0,
        float acc[RB][6]) {
    float4 s[6];
    #pragma unroll
    for (int c = 0; c < 6; c++)
        s[c] = *(const float4*)(Splanes + (size_t)c * BN + (size_t)b * N + c0);
    float4 w[RB];
    #pragma unroll
    for (int r = 0; r < RB; r++)
        w[r] = *(const float4*)(beta + (size_t)(grow0 + r) * N + c0);

    float csum0 = 0.f, csum1 = 0.f, csum2 = 0.f, csum3 = 0.f;
    #pragma unroll
    for (int r = 0; r < RB; r++) {
        csum0 += w[r].x; csum1 += w[r].y; csum2 += w[r].z; csum3 += w[r].w;
    }
    *(float4*)(partial + ((size_t)b * chunksPerB + chunk) * N + c0) =
        make_float4(csum0, csum1, csum2, csum3);
    #pragma unroll
    for (int r = 0; r < RB; r++)
        #pragma unroll
        for (int c = 0; c < 6; c++)
            acc[r][c] += w[r].x*s[c].x + w[r].y*s[c].y + w[r].z*s[c].z + w[r].w*s[c].w;
}

__global__ __launch_bounds__(256) void fused_beta_kernel(
        const float* __restrict__ beta,
        const float* __restrict__ Splanes,
        float* __restrict__ T,
        float* __restrict__ partial,  // B * (N/RB) * N
        int B, int N, int BN) {
    int tid = threadIdx.x;
    int grow0 = blockIdx.x * RB;
    int b = grow0 / N;
    int chunksPerB = N / RB;
    int chunk = (grow0 - b * N) / RB;

    float acc[RB][6];
    #pragma unroll
    for (int r = 0; r < RB; r++)
        #pragma unroll
        for (int c = 0; c < 6; c++) acc[r][c] = 0.0f;

    if (N == 2048) {
        // straight-line both tiles: all loads issued before compute (ILP)
        int c0 = 4 * tid;
        int c1 = 1024 + 4 * tid;
        // tile 0 loads
        float4 s0[6], w0[RB], s1[6], w1[RB];
        #pragma unroll
        for (int c = 0; c < 6; c++)
            s0[c] = *(const float4*)(Splanes + (size_t)c * BN + (size_t)b * N + c0);
        #pragma unroll
        for (int r = 0; r < RB; r++)
            w0[r] = *(const float4*)(beta + (size_t)(grow0 + r) * N + c0);
        // tile 1 loads
        #pragma unroll
        for (int c = 0; c < 6; c++)
            s1[c] = *(const float4*)(Splanes + (size_t)c * BN + (size_t)b * N + c1);
        #pragma unroll
        for (int r = 0; r < RB; r++)
            w1[r] = *(const float4*)(beta + (size_t)(grow0 + r) * N + c1);

        // tile 0 compute
        {
            float csum0=0.f,csum1=0.f,csum2=0.f,csum3=0.f;
            #pragma unroll
            for (int r = 0; r < RB; r++) { csum0+=w0[r].x; csum1+=w0[r].y; csum2+=w0[r].z; csum3+=w0[r].w; }
            *(float4*)(partial + ((size_t)b * chunksPerB + chunk) * N + c0) =
                make_float4(csum0,csum1,csum2,csum3);
            #pragma unroll
            for (int r = 0; r < RB; r++)
                #pragma unroll
                for (int c = 0; c < 6; c++)
                    acc[r][c] += w0[r].x*s0[c].x + w0[r].y*s0[c].y + w0[r].z*s0[c].z + w0[r].w*s0[c].w;
        }
        // tile 1 compute
        {
            float csum0=0.f,csum1=0.f,csum2=0.f,csum3=0.f;
            #pragma unroll
            for (int r = 0; r < RB; r++) { csum0+=w1[r].x; csum1+=w1[r].y; csum2+=w1[r].z; csum3+=w1[r].w; }
            *(float4*)(partial + ((size_t)b * chunksPerB + chunk) * N + c1) =
                make_float4(csum0,csum1,csum2,csum3);
            #pragma unroll
            for (int r = 0; r < RB; r++)
                #pragma unroll
                for (int c = 0; c < 6; c++)
                    acc[r][c] += w1[r].x*s1[c].x + w1[r].y*s1[c].y + w1[r].z*s1[c].z + w1[r].w*s1[c].w;
        }
    } else {
        int jtiles = N / 1024;
        for (int jt = 0; jt < jtiles; jt++)
            beta_tile(beta, Splanes, partial, grow0, b, N, BN,
                      chunksPerB, chunk, jt * 1024 + 4 * tid, acc);
    }

    // ---- LDS transpose reduction: 256 threads x 48 values -> 48 sums ----
    __shared__ float red[256][48];
    __shared__ float red2[4][48];
    #pragma unroll
    for (int r = 0; r < RB; r++)
        #pragma unroll
        for (int c = 0; c < 6; c++)
            red[tid][r * 6 + c] = acc[r][c];
    __syncthreads();
    if (tid < 192) {
        int v = tid % 48, grp = tid / 48;
        float s = 0.0f;
        #pragma unroll 8
        for (int r = 0; r < 64; r++) s += red[grp * 64 + r][v];
        red2[grp][v] = s;
    }
    __syncthreads();
    if (tid < 48) {
        float v = red2[0][tid] + red2[1][tid] + red2[2][tid] + red2[3][tid];
        T[(size_t)grow0 * 6 + tid] = v;
    }
}

// ---------- kernel 3: finalize (128 blocks, 32 pts, float4 col-sum) ----------
__global__ __launch_bounds__(256) void finalize_kernel(
        const float* __restrict__ Sp,
        const float* __restrict__ Sq,
        const float* __restrict__ phi,
        const float* __restrict__ T,
        const float* __restrict__ partial, // B*(N/RB)*N
        float* __restrict__ out,
        int B, int N) {
    int tid  = threadIdx.x;
    int p0   = blockIdx.x * 32;     // 32 points per block
    int BN   = B * N;
    int b    = p0 / N;
    int i0   = p0 - b * N;
    int chunks = N / RB;            // 256

    __shared__ float4 redc[32][8];  // [group][col-quad]
    __shared__ float sp_s[288], sq_s[288], ph_s[96], t_s[192];
    __shared__ float o1_s[288], o2_s[288];

    // --- float4 column-sum: 32 groups x 8 chunks each, 8 col-quads ---
    {
        int m = tid & 7;            // col-quad 0..7 (32 cols)
        int g = tid >> 3;           // group 0..31
        int cpg = chunks / 32;      // 8
        float4 a = make_float4(0.f, 0.f, 0.f, 0.f);
        const float4* pp = (const float4*)(partial + ((size_t)b * chunks + g * cpg) * N + i0) + m;
        int stepq = N >> 2;
        #pragma unroll
        for (int k = 0; k < 8; k++) {
            float4 v = *pp; pp += stepq;
            a.x += v.x; a.y += v.y; a.z += v.z; a.w += v.w;
        }
        redc[g][m] = a;
    }

    // --- stage per-point inputs (coalesced float4) ---
    {
        const float4* s1 = (const float4*)(Sp + (size_t)p0 * 9);
        const float4* s2 = (const float4*)(Sq + (size_t)p0 * 9);
        if (tid < 72) { ((float4*)sp_s)[tid] = s1[tid]; ((float4*)sq_s)[tid] = s2[tid]; }
        const float4* s3 = (const float4*)(phi + (size_t)p0 * 3);
        if (tid < 24) ((float4*)ph_s)[tid] = s3[tid];
        const float4* s4 = (const float4*)(T + (size_t)p0 * 6);
        if (tid < 48) ((float4*)t_s)[tid] = s4[tid];
    }
    __syncthreads();

    if (tid < 32) {
        float cs = 0.0f;
        #pragma unroll
        for (int g = 0; g < 32; g++) {
            const float* rc = (const float*)&redc[g][tid >> 2];
            cs += rc[tid & 3];
        }

        float m[3][3], lp[3][3], lq[3][3];
        #pragma unroll
        for (int i = 0; i < 3; i++)
            #pragma unroll
            for (int j = 0; j < 3; j++) m[i][j] = sq_s[tid*9 + i*3 + j];
        m[0][0] += EPS_REG; m[1][1] += EPS_REG; m[2][2] += EPS_REG;
        sym_inv3(m, lq);
        #pragma unroll
        for (int i = 0; i < 3; i++)
            #pragma unroll
            for (int j = 0; j < 3; j++) m[i][j] = sp_s[tid*9 + i*3 + j];
        m[0][0] += EPS_REG; m[1][1] += EPS_REG; m[2][2] += EPS_REG;
        sym_inv3(m, lp);

        float R[3][3];
        rodrigues(ph_s[tid*3], ph_s[tid*3+1], ph_s[tid*3+2], R);

        const float* tp = t_s + tid * 6;
        float Tm[3][3] = {{tp[0],tp[1],tp[2]},{tp[1],tp[3],tp[4]},{tp[2],tp[4],tp[5]}};

        float U[3][3], M[3][3];
        #pragma unroll
        for (int ii = 0; ii < 3; ii++)
            #pragma unroll
            for (int jj = 0; jj < 3; jj++)
                U[ii][jj] = R[ii][0]*Tm[0][jj] + R[ii][1]*Tm[1][jj] + R[ii][2]*Tm[2][jj];
        #pragma unroll
        for (int ii = 0; ii < 3; ii++)
            #pragma unroll
            for (int jj = 0; jj < 3; jj++) {
                float min_ij = U[ii][0]*R[jj][0] + U[ii][1]*R[jj][1] + U[ii][2]*R[jj][2];
                M[ii][jj] = lp[ii][jj] + min_ij + cs * lq[ii][jj];
            }
        float A[3][3];
        #pragma unroll
        for (int ii = 0; ii < 3; ii++)
            #pragma unroll
            for (int jj = 0; jj < 3; jj++) A[ii][jj] = 0.5f * (M[ii][jj] + M[jj][ii]);

        float V[3][3] = {{1,0,0},{0,1,0},{0,0,1}};
        #pragma unroll
        for (int sweep = 0; sweep < 6; sweep++) {
            jrot(A, V, 0, 1);
            jrot(A, V, 0, 2);
            jrot(A, V, 1, 2);
        }
        float w0 = fmaxf(A[0][0], MIN_EIG_F);
        float w1 = fmaxf(A[1][1], MIN_EIG_F);
        float w2 = fmaxf(A[2][2], MIN_EIG_F);
        float iw0 = 1.0f/w0, iw1 = 1.0f/w1, iw2 = 1.0f/w2;

        #pragma unroll
        for (int ii = 0; ii < 3; ii++)
            #pragma unroll
            for (int jj = 0; jj < 3; jj++) {
                o1_s[tid*9 + ii*3 + jj] = V[ii][0]*w0*V[jj][0] + V[ii][1]*w1*V[jj][1] + V[ii][2]*w2*V[jj][2];
                o2_s[tid*9 + ii*3 + jj] = V[ii][0]*iw0*V[jj][0] + V[ii][1]*iw1*V[jj][1] + V[ii][2]*iw2*V[jj][2];
            }
    }
    __syncthreads();

    float4* d1 = (float4*)(out + (size_t)p0 * 9);
    float4* d2 = (float4*)(out + (size_t)BN * 9 + (size_t)p0 * 9);
    if (tid < 72) { d1[tid] = ((float4*)o1_s)[tid]; d2[tid] = ((float4*)o2_s)[tid]; }
}

extern "C" void kernel_launch(void* const* d_in, const int* in_sizes, int n_in,
                              void* d_out, int out_size, void* d_ws, size_t ws_size,
                              hipStream_t stream) {
    const float* Sp   = (const float*)d_in[0];
    const float* Sq   = (const float*)d_in[1];
    const float* phi  = (const float*)d_in[2];
    const float* beta = (const float*)d_in[3];

    int BN = in_sizes[2] / 3;                 // B*N
    int N  = (int)((long long)in_sizes[3] / BN);
    int B  = BN / N;

    float* ws = (float*)d_ws;
    float* Splanes = ws;                        // 6*BN
    float* T       = Splanes + (size_t)BN * 6;  // BN*6
    float* partial = T + (size_t)BN * 6;        // B*(N/RB)*N

    float* outf = (float*)d_out;

    precompute_S_kernel<<<BN / 64, 64, 0, stream>>>(Sq, phi, Splanes, BN);

    fused_beta_kernel<<<BN / RB, 256, 0, stream>>>(beta, Splanes, T, partial, B, N, BN);

    finalize_kernel<<<BN / 32, 256, 0, stream>>>(Sp, Sq, phi, T, partial, outf, B, N);
}